// Round 1
// baseline (163.458 us; speedup 1.0000x reference)
//
#include <hip/hip_runtime.h>
#include <hip/hip_bf16.h>

#define NE 8192
#define BATCH 64
#define NNZT (NE * 32)
#define BK 64
#define SAK 72   // padded LDS row stride (bf16 elems): 144 B, 16B-aligned, conflict-free
#define TN 16    // N-tile (i columns) per block

typedef float f32x4 __attribute__((ext_vector_type(4)));
typedef short s16x8 __attribute__((ext_vector_type(8)));

__device__ __forceinline__ unsigned short f2bf(float f) {
  unsigned u = __builtin_bit_cast(unsigned, f);
  return (unsigned short)((u + 0x7FFFu + ((u >> 16) & 1u)) >> 16);  // RNE
}

// x fp32 [64][8192] -> bf16 (as ushort)
__global__ void k_convert_x(const float* __restrict__ x, unsigned short* __restrict__ xb) {
  int i = (blockIdx.x * 256 + threadIdx.x) * 4;
  float4 v = *reinterpret_cast<const float4*>(x + i);
  *reinterpret_cast<ushort4*>(xb + i) =
      make_ushort4(f2bf(v.x), f2bf(v.y), f2bf(v.z), f2bf(v.w));
}

__global__ void k_zero(float* __restrict__ p) {
  int i = (blockIdx.x * 256 + threadIdx.x) * 4;
  *reinterpret_cast<float4*>(p + i) = make_float4(0.f, 0.f, 0.f, 0.f);
}

// h = x @ W^T, stored transposed: ht[i][b], i in [0,8192), b in [0,64)
// Block: 256 thr (4 waves). Output tile 64(b) x 16(i). Grid 512.
__global__ __launch_bounds__(256, 2) void k_gemm(const unsigned short* __restrict__ xb,
                                                 const float* __restrict__ W,
                                                 float* __restrict__ ht) {
  __shared__ __align__(16) unsigned short sA[BATCH * SAK];  // x tile [64][BK]
  __shared__ __align__(16) unsigned short sB[TN * SAK];     // W tile [16][BK]
  const int tid = threadIdx.x;
  const int i0 = blockIdx.x * TN;

  // staging: x tile 64x64 bf16 -> 32B/thread (two uint4)
  const int rA = tid >> 2, cA = (tid & 3) * 16;
  // staging: W tile 16x64 fp32 -> 4 floats/thread -> 4 bf16
  const int rB = tid >> 4, cB = (tid & 15) * 4;

  const unsigned short* xptr = xb + rA * NE + cA;
  const float* wptr = W + (size_t)(i0 + rB) * NE + cB;
  unsigned short* sAp = sA + rA * SAK + cA;
  unsigned short* sBp = sB + rB * SAK + cB;

  const int wave = tid >> 6, lane = tid & 63;
  const int lrow = lane & 15, kofs = (lane >> 4) * 8;
  // A frag: x rows (b) = wave*16 + lrow ; B frag: W rows (i) = lrow
  const unsigned short* aRd = sA + (wave * 16 + lrow) * SAK + kofs;
  const unsigned short* bRd = sB + lrow * SAK + kofs;

  f32x4 acc = {0.f, 0.f, 0.f, 0.f};

  // register prefetch of tile k0=0
  uint4 xr0 = *reinterpret_cast<const uint4*>(xptr);
  uint4 xr1 = *reinterpret_cast<const uint4*>(xptr + 8);
  float4 wr = *reinterpret_cast<const float4*>(wptr);

  for (int k0 = 0;;) {
    *reinterpret_cast<uint4*>(sAp) = xr0;
    *reinterpret_cast<uint4*>(sAp + 8) = xr1;
    *reinterpret_cast<ushort4*>(sBp) =
        make_ushort4(f2bf(wr.x), f2bf(wr.y), f2bf(wr.z), f2bf(wr.w));
    __syncthreads();
    k0 += BK;
    if (k0 < NE) {  // prefetch next tile; latency hides under MFMA + barrier
      xr0 = *reinterpret_cast<const uint4*>(xptr + k0);
      xr1 = *reinterpret_cast<const uint4*>(xptr + k0 + 8);
      wr = *reinterpret_cast<const float4*>(wptr + k0);
    }
#pragma unroll
    for (int ks = 0; ks < 2; ++ks) {
      s16x8 bfr = *reinterpret_cast<const s16x8*>(bRd + ks * 32);
      s16x8 afr = *reinterpret_cast<const s16x8*>(aRd + ks * 32);
      acc = __builtin_amdgcn_mfma_f32_16x16x32_bf16(afr, bfr, acc, 0, 0, 0);
    }
    if (k0 >= NE) break;
    __syncthreads();
  }

  // C/D layout: col = lane&15 (i), row = (lane>>4)*4 + r (b within wave's 16)
  float* hp = ht + (size_t)(i0 + lrow) * BATCH + wave * 16 + (lane >> 4) * 4;
  *reinterpret_cast<f32x4*>(hp) = acc;
}

// out_t[c][b] += ht[r][b] * w  for each nnz. One wave per nnz-chunk, lane = b.
__global__ void k_scatter(const float* __restrict__ ht, const float* __restrict__ sw,
                          const int* __restrict__ rows, const int* __restrict__ cols,
                          float* __restrict__ out_t) {
  const int w = (blockIdx.x * 256 + threadIdx.x) >> 6;  // 0..4095
  const int lane = threadIdx.x & 63;
  const int n0 = w * (NNZT / 4096);                     // 64 nnz per wave
#pragma unroll 4
  for (int n = n0; n < n0 + (NNZT / 4096); ++n) {
    const int r = rows[n];
    const int c = cols[n];
    const float wv = sw[n];
    atomicAdd(out_t + (size_t)c * BATCH + lane, ht[(size_t)r * BATCH + lane] * wv);
  }
}

// out[b][j] = leaky(out_t[j][b]) via LDS transpose. Grid 128 (j-tiles of 64).
__global__ void k_final(const float* __restrict__ out_t, float* __restrict__ out) {
  __shared__ float tile[64][65];
  const int t = threadIdx.x;
  const int j0 = blockIdx.x * 64;
  {
    const int jl = t >> 2, b0 = (t & 3) * 16;
    const float* src = out_t + (size_t)(j0 + jl) * BATCH + b0;
#pragma unroll
    for (int e = 0; e < 16; e += 4) {
      float4 v = *reinterpret_cast<const float4*>(src + e);
      tile[jl][b0 + e + 0] = v.x;
      tile[jl][b0 + e + 1] = v.y;
      tile[jl][b0 + e + 2] = v.z;
      tile[jl][b0 + e + 3] = v.w;
    }
  }
  __syncthreads();
  {
    const int bl = t >> 2, js = (t & 3) * 16;
    float* dst = out + (size_t)bl * NE + j0 + js;
#pragma unroll
    for (int e = 0; e < 16; e += 4) {
      float a0 = tile[js + e + 0][bl];
      float a1 = tile[js + e + 1][bl];
      float a2 = tile[js + e + 2][bl];
      float a3 = tile[js + e + 3][bl];
      float4 v;
      v.x = a0 >= 0.f ? a0 : 0.001f * a0;
      v.y = a1 >= 0.f ? a1 : 0.001f * a1;
      v.z = a2 >= 0.f ? a2 : 0.001f * a2;
      v.w = a3 >= 0.f ? a3 : 0.001f * a3;
      *reinterpret_cast<float4*>(dst + e) = v;
    }
  }
}

extern "C" void kernel_launch(void* const* d_in, const int* in_sizes, int n_in,
                              void* d_out, int out_size, void* d_ws, size_t ws_size,
                              hipStream_t stream) {
  const float* x = (const float*)d_in[0];
  const float* W = (const float*)d_in[1];
  const float* sw = (const float*)d_in[2];
  const int* idx = (const int*)d_in[3];  // [2][NNZ]: rows then cols
  float* out = (float*)d_out;

  char* ws = (char*)d_ws;
  float* ht = (float*)ws;                                   // 2 MB: ht[8192][64]
  unsigned short* xbf = (unsigned short*)(ws + (2 << 20));  // 1 MB: x in bf16
  float* out_t = (float*)(ws + (3 << 20));                  // 2 MB: out_t[8192][64]

  k_convert_x<<<512, 256, 0, stream>>>(x, xbf);
  k_zero<<<512, 256, 0, stream>>>(out_t);
  k_gemm<<<512, 256, 0, stream>>>(xbf, W, ht);
  k_scatter<<<1024, 256, 0, stream>>>(ht, sw, idx, idx + NNZT, out_t);
  k_final<<<128, 256, 0, stream>>>(out_t, out);
}